// Round 12
// baseline (320.170 us; speedup 1.0000x reference)
//
#include <hip/hip_runtime.h>

#define B_   16
#define CIN  128
#define NPT  2048
#define COUT 256
#define KNN  20
#define KEEP 16
#define SIFT 32
#define EPS  1e-5f
#define DBIAS 256.0f   // must exceed max_q |x_q|^2 (chi2_128 max ~210 over 32k)

// workspace byte offsets
#define SQ_OFF   0ull                          // sqh: 32768 f (fp16-rounded |x|^2)
#define IDX_OFF  131072ull                     // 16*2048*20 i32
#define UT_OFF   2752512ull                    // fp16 uT: 16*2048*256 h = 16.8M (fallback: f32)
#define VT_OFF   36306944ull                   // fp16 vT (fallback: f32)
#define GS_OFF   69861376ull                   // 2*256 double
#define ST_OFF   69865472ull                   // 2*256 f
// fused-path buffers (only when ws_size is large enough)
#define AMAX_OFF 69871616ull                   // fp16 aMax 16.8M; region [0,33.5M) also hosts xT/xhT
#define AMIN_OFF 103426048ull                  // fp16 aMin 16.8M; also hosts svG (4MB) until refine
#define WS_NEED_FUSED 136980480ull
// Fused mode: xT (fp32 16.8M) + xhT (fp16 8.4M) live in the AMAX region; xT
// is dead after refine, so gather_stats' fp16 aMax (16.8M) overwrites the xT
// slot. Survivor ids (4 MB) live at AMIN_OFF: written by knn, read by
// refine, then gather_stats' fp16 aMin overwrites. uT/vT are fp16, written
// by prep's fused u/v GEMM (no separate uv kernel, no Wu/Wv buffers).
#define XT_OFF   UT_OFF
#define XHT_OFF  VT_OFF

typedef _Float16 f16x8 __attribute__((ext_vector_type(8)));
typedef _Float16 f16x4 __attribute__((ext_vector_type(4)));
typedef float    f32x4 __attribute__((ext_vector_type(4)));
typedef float    f32x2 __attribute__((ext_vector_type(2)));

// ------------------------------------ prep: xT, xhT, sqh (+fused u/v GEMM)
// 1D 512-block grid, XCD-pinned with the SAME decode as knn/refine/gather so
// every slice of xhT/xT/uT/vT for batch b stays on one XCD's L2.
// After the transpose, the block reuses its x-tile (still in Ls) to compute
// the u/v GEMM for this (b, n0) tile directly: B-fragments are fp16 casts of
// Ls values (bit-identical to xhT), A-fragments come from fp32 W with
// w1-w2 in fp32 then fp16 cast (bit-identical to the old wconv+uv path).
// Eliminates the separate uv kernel and its 33.5MB xhT re-read.
// Block 0 also zeroes gsum (replaces the hipMemsetAsync dispatch).
__global__ __launch_bounds__(256) void prep_kernel(const float* __restrict__ x,
                                                   const float* __restrict__ W,
                                                   float* __restrict__ xT,
                                                   _Float16* __restrict__ xhT,
                                                   float* __restrict__ sqh,
                                                   _Float16* __restrict__ uT,
                                                   _Float16* __restrict__ vT,
                                                   double* __restrict__ gsum) {
    __shared__ float Ls[128 * 68];
    __shared__ float ps[4 * 64];
    const int id  = blockIdx.x;                // 512, XCD-pinned
    const int xcd = id & 7, qq = id >> 3;      // qq 0..63
    const int b   = xcd + ((qq >> 5) << 3);
    const int n0  = (qq & 31) * 64;
    const int t = threadIdx.x;
    if (id == 0) {                             // fold gsum zeroing (512 doubles)
        gsum[t] = 0.0;
        gsum[256 + t] = 0.0;
    }
    const float* xb = x + (size_t)b * CIN * NPT;
    #pragma unroll
    for (int e = 0; e < 8; ++e) {              // 2048 float4 loads, coalesced
        int f = e * 256 + t;
        int c = f >> 4, n4 = (f & 15) << 2;
        *(float4*)&Ls[c * 68 + n4] = *(const float4*)&xb[(size_t)c * NPT + n0 + n4];
    }
    __syncthreads();
    {                                          // sq partials on fp16-rounded vals
        int nl = t & 63, part = t >> 6;
        float acc = 0.f;
        #pragma unroll
        for (int j = 0; j < 32; ++j) {
            float vh = (float)(_Float16)Ls[(part * 32 + j) * 68 + nl];
            acc += vh * vh;
        }
        ps[part * 64 + nl] = acc;
    }
    #pragma unroll
    for (int e = 0; e < 2; ++e) {              // transpose writes: (nl, 16-c chunk)
        int u = e * 256 + t;
        int nl = u >> 3, ck = (u & 7) << 4;
        float vv[16];
        #pragma unroll
        for (int j = 0; j < 16; ++j) vv[j] = Ls[(ck + j) * 68 + nl];
        size_t row = (size_t)b * NPT + n0 + nl;
        #pragma unroll
        for (int j = 0; j < 4; ++j) {
            float4 w = {vv[4 * j], vv[4 * j + 1], vv[4 * j + 2], vv[4 * j + 3]};
            *(float4*)&xT[row * CIN + ck + 4 * j] = w;
        }
        f16x8 h0, h1;
        #pragma unroll
        for (int j = 0; j < 8; ++j) { h0[j] = (_Float16)vv[j]; h1[j] = (_Float16)vv[8 + j]; }
        *(f16x8*)&xhT[row * CIN + ck] = h0;
        *(f16x8*)&xhT[row * CIN + ck + 8] = h1;
    }
    __syncthreads();
    if (t < 64) sqh[b * NPT + n0 + t] = ps[t] + ps[64 + t] + ps[128 + t] + ps[192 + t];

    if (uT == nullptr) return;                 // fallback path: no fused u/v

    // ---- fused u/v GEMM for this (b, n0) tile (indexing replicates the
    // verified uv_gemm_h fragment semantics exactly) ----
    const int lane = t & 63, w = t >> 6, l15 = lane & 15, quad = lane >> 4;
    f16x8 bf[4];                               // bf[ks][j] = xh[n][ks*32+quad*8+j]
    #pragma unroll
    for (int ks = 0; ks < 4; ++ks)
        #pragma unroll
        for (int j = 0; j < 8; ++j)
            bf[ks][j] = (_Float16)Ls[(ks * 32 + quad * 8 + j) * 68 + (w * 16 + l15)];
    const int n = n0 + w * 16 + l15;
    #pragma unroll 1
    for (int ot = 0; ot < 16; ++ot) {
        const float* wrow = W + (size_t)(ot * 16 + l15) * 256;
        f32x4 au = (f32x4){0.f, 0.f, 0.f, 0.f};
        f32x4 av = (f32x4){0.f, 0.f, 0.f, 0.f};
        #pragma unroll
        for (int ks = 0; ks < 4; ++ks) {
            const int c0 = quad * 8 + ks * 32;
            float4 wa = *(const float4*)&wrow[c0];
            float4 wb = *(const float4*)&wrow[c0 + 4];
            float4 wc = *(const float4*)&wrow[128 + c0];
            float4 wd = *(const float4*)&wrow[128 + c0 + 4];
            f16x8 a_u, a_v;
            a_u[0] = (_Float16)(wa.x - wc.x); a_v[0] = (_Float16)wc.x;
            a_u[1] = (_Float16)(wa.y - wc.y); a_v[1] = (_Float16)wc.y;
            a_u[2] = (_Float16)(wa.z - wc.z); a_v[2] = (_Float16)wc.z;
            a_u[3] = (_Float16)(wa.w - wc.w); a_v[3] = (_Float16)wc.w;
            a_u[4] = (_Float16)(wb.x - wd.x); a_v[4] = (_Float16)wd.x;
            a_u[5] = (_Float16)(wb.y - wd.y); a_v[5] = (_Float16)wd.y;
            a_u[6] = (_Float16)(wb.z - wd.z); a_v[6] = (_Float16)wd.z;
            a_u[7] = (_Float16)(wb.w - wd.w); a_v[7] = (_Float16)wd.w;
            au = __builtin_amdgcn_mfma_f32_16x16x32_f16(a_u, bf[ks], au, 0, 0, 0);
            av = __builtin_amdgcn_mfma_f32_16x16x32_f16(a_v, bf[ks], av, 0, 0, 0);
        }
        size_t base = ((size_t)b * NPT + n) * COUT + ot * 16 + quad * 4;
        f16x4 auh = {(_Float16)au[0], (_Float16)au[1], (_Float16)au[2], (_Float16)au[3]};
        f16x4 avh = {(_Float16)av[0], (_Float16)av[1], (_Float16)av[2], (_Float16)av[3]};
        *(f16x4*)&uT[base] = auh;
        *(f16x4*)&vT[base] = avh;
    }
}

// -------------------------------------------- 64-row fragment staging via DMA
__device__ __forceinline__ void stage_pts(const _Float16* __restrict__ xhb,
                                          _Float16* buf, int base_n, int t) {
    const int l15 = t & 15, ks = t >> 6;
    const int quad = (t >> 4) & 3;
    const int c = ks * 32 + quad * 8;
    #pragma unroll
    for (int e = 0; e < 4; ++e) {
        const int n = base_n + e * 16 + l15;
        const _Float16* src = xhb + (size_t)n * CIN + c;
        _Float16* dst = buf + (size_t)(e * 256 + (t & 192)) * 8;   // wave-uniform base
        __builtin_amdgcn_global_load_lds(
            (const __attribute__((address_space(1))) void*)src,
            (__attribute__((address_space(3))) void*)dst, 16, 0, 0);
    }
}

// -------------------------------------------- per-wave 16-row tile staging
// srcl = per-lane ptr: row (m_base + lane&15), chan (lane>>4)*8.
// dst elem = e*512 + lane*8 holds (m = lane&15, chans (lane>>4)*8 + e*32 ..+8)
// -> B-fragment order bf[ks] = tile[ks*512 + lane*8].
__device__ __forceinline__ void stage_tile16(const _Float16* __restrict__ srcl,
                                             _Float16* dsthalf) {
    #pragma unroll
    for (int e = 0; e < 4; ++e) {
        __builtin_amdgcn_global_load_lds(
            (const __attribute__((address_space(1))) void*)(srcl + e * 32),
            (__attribute__((address_space(3))) void*)(dsthalf + (size_t)e * 512),
            16, 0, 0);
    }
}

// ---------------------------------------------------------------- KNN (split)
// ROUND-6 LOCKED CONFIG (measured ~72 us, VGPR 88): barrier-free main loop,
// 4-wave 256-thread blocks, 512 blocks XCD-pinned; each wave owns m-tiles
// (tile%4==wv) for ALL 64 queries; A-frags hoisted; per-wave double-buffered
// 16-m B tiles via global_load_lds; packed keys (21-bit chopped distance |
// 11-bit m) through wave-private Dt; thread=query batch-bitonic top-16.
// Tail stops after the quantized sift -> 32 survivor ids per query to global.
__global__ __launch_bounds__(256, 2) void knn_kernel(const _Float16* __restrict__ xhT,
                                                     const float* __restrict__ sqh,
                                                     int* __restrict__ surv_out) {
    __shared__ char smraw[59392];
    // [0,18432)      Dt: wave wv at wv*4608, [64 q][18 f] stride-18 rows
    //                (A-frag staging [0,16384) lives here before Dt starts)
    // [18432,26624)  sqm: 2048 f (biased +DBIAS)
    // [26624,59392)  per-wave B dbuf: wv at 26624+wv*8192, halves of 4096 B
    // tail aliases [0,16640): Keys
    _Float16* bufA = (_Float16*)smraw;
    float*    sqm  = (float*)(smraw + 18432);

    const int id  = blockIdx.x;                     // 512, XCD-pinned
    const int xcd = id & 7, qq = id >> 3;           // qq 0..63
    const int b   = xcd + ((qq >> 5) << 3);         // 2 batches per XCD
    const int q0  = (qq & 31) * 64;
    const int t  = threadIdx.x;
    const int lane = t & 63, wv = t >> 6;
    const int l15 = lane & 15, quad = lane >> 4;
    const _Float16* xhb = xhT + (size_t)b * NPT * CIN;

    #pragma unroll
    for (int e = 0; e < 8; ++e)
        sqm[e * 256 + t] = sqh[b * NPT + e * 256 + t] + DBIAS;

    stage_pts(xhb, bufA, q0, t);                    // A fragments (64 queries)
    __syncthreads();                                // A + sqm ready (drains vmcnt)

    f16x8 af[4][4];                                 // all 64 q in registers
    #pragma unroll
    for (int qh = 0; qh < 4; ++qh)
        #pragma unroll
        for (int ks = 0; ks < 4; ++ks)
            af[qh][ks] = *(const f16x8*)(bufA + (size_t)((qh * 4 + ks) * 64 + lane) * 8);
    __syncthreads();                                // A region free -> Dt may start

    _Float16* wbuf = (_Float16*)(smraw + 26624 + wv * 8192);
    float*    DtW  = (float*)(smraw + wv * 4608);
    const _Float16* srcl = xhb + (size_t)(wv * 16 + l15) * CIN + quad * 8;

    stage_tile16(srcl, wbuf);                       // step 0 -> half 0

    float bd[KEEP];
    #pragma unroll
    for (int i = 0; i < KEEP; ++i) bd[i] = 3.0e38f;

    #pragma unroll 1
    for (int ss = 0; ss < 32; ++ss) {
        const int mb = ss * 64 + wv * 16;           // this wave's tile base
        asm volatile("s_waitcnt vmcnt(0)" ::: "memory");   // cur half staged
        __builtin_amdgcn_sched_barrier(0);
        const _Float16* cur = wbuf + (ss & 1) * 2048;
        f16x8 bf[4];
        #pragma unroll
        for (int ks = 0; ks < 4; ++ks)
            bf[ks] = *(const f16x8*)(cur + ks * 512 + lane * 8);
        float sm_ = sqm[mb + l15];                  // = |xm|^2 + DBIAS
        asm volatile("s_waitcnt lgkmcnt(0)" ::: "memory");  // bf in regs
        __builtin_amdgcn_sched_barrier(0);
        if (ss < 31)                                // prefetch next tile
            stage_tile16(srcl + (size_t)(ss + 1) * 64 * CIN,
                         wbuf + ((ss + 1) & 1) * 2048);
        __builtin_amdgcn_sched_barrier(0);
        f32x4 acc[4];
        #pragma unroll
        for (int qh = 0; qh < 4; ++qh) acc[qh] = (f32x4){0.f, 0.f, 0.f, 0.f};
        #pragma unroll
        for (int ks = 0; ks < 4; ++ks)
            #pragma unroll
            for (int qh = 0; qh < 4; ++qh)
                acc[qh] = __builtin_amdgcn_mfma_f32_16x16x32_f16(af[qh][ks], bf[ks], acc[qh], 0, 0, 0);
        // pack keys (unique: chopped distance | full m), wave-private Dt
        const unsigned om = (unsigned)(mb + l15);
        #pragma unroll
        for (int qh = 0; qh < 4; ++qh) {
            #pragma unroll
            for (int rg = 0; rg < 4; ++rg) {        // D row = q (A free dim)
                int q = qh * 16 + quad * 4 + rg;
                float d = sm_ - 2.f * acc[qh][rg];
                DtW[q * 18 + l15] = __uint_as_float((__float_as_uint(d) & 0xFFFFF800u) | om);
            }
        }
        // read own query row (16 keys) -- same wave wrote it; in-order DS
        float nk[16];
        {
            const float* myrow = DtW + lane * 18;
            #pragma unroll
            for (int p = 0; p < 8; ++p) {
                f32x2 v = *(const f32x2*)(myrow + 2 * p);
                nk[2 * p] = v[0]; nk[2 * p + 1] = v[1];
            }
        }
        // bitonic sort nk ascending (keys > 0: float order == uint order)
        #pragma unroll
        for (int kk = 2; kk <= 16; kk <<= 1) {
            #pragma unroll
            for (int j = kk >> 1; j > 0; j >>= 1) {
                #pragma unroll
                for (int i = 0; i < 16; ++i) {
                    int p = i ^ j;
                    if (p > i) {
                        float a = nk[i], c = nk[p];
                        float lo = fminf(a, c), hi = fmaxf(a, c);
                        if ((i & kk) == 0) { nk[i] = lo; nk[p] = hi; }
                        else               { nk[i] = hi; nk[p] = lo; }
                    }
                }
            }
        }
        // bottom-16 of (bd ∪ nk): min(asc bd, desc nk) is bitonic, then clean
        #pragma unroll
        for (int i = 0; i < 16; ++i) bd[i] = fminf(bd[i], nk[15 - i]);
        #pragma unroll
        for (int j = 8; j > 0; j >>= 1) {
            #pragma unroll
            for (int i = 0; i < 16; ++i) {
                int p = i ^ j;
                if (p > i) {
                    float a = bd[i], c = bd[p];
                    bd[i] = fminf(a, c);
                    bd[p] = fmaxf(a, c);
                }
            }
        }
        // bd stays sorted ascending across steps
    }

    __syncthreads();                               // all waves done; alias smraw

    // ---- quantized pre-sift: rank-count the 64 packed keys per query ----
    // thread (wv, lane) holds subset-wv's top-16 for query q0+lane.
    float* Keys = (float*)smraw;                   // [64][65] f = 16640 B
    #pragma unroll
    for (int i = 0; i < KEEP; ++i)
        Keys[lane * 65 + wv * KEEP + i] = bd[i];
    __syncthreads();
    {
        int cnt[KEEP];
        #pragma unroll
        for (int i = 0; i < KEEP; ++i) cnt[i] = 0;
        #pragma unroll 4
        for (int j = 0; j < 64; ++j) {
            float kj = Keys[lane * 65 + j];
            #pragma unroll
            for (int i = 0; i < KEEP; ++i)
                cnt[i] += (kj < bd[i]) ? 1 : 0;
        }
        // ranks are unique (keys unique) -> exactly 32 survivors per query
        int* dst = surv_out + ((size_t)b * NPT + q0 + lane) * SIFT;
        #pragma unroll
        for (int i = 0; i < KEEP; ++i)
            if (cnt[i] < SIFT)
                dst[cnt[i]] = (int)(__float_as_uint(bd[i]) & 0x7FFu);
    }
}

// ---------------------------------------------------------------- refine
// Exact fp64 refinement. 2048 blocks, XCD-pinned (2 xT slices per XCD,
// L2-resident). 8-lane groups process one (q, survivor) pair; lane j covers
// dims [16j,16j+16) -> contiguous 512 B group read. Q-rows cached in LDS.
__global__ __launch_bounds__(256, 4) void refine_kernel(const float* __restrict__ xT,
                                                        const int* __restrict__ surv,
                                                        int* __restrict__ knn_out) {
    __shared__ float  Qs[16 * 128];                // 8 KB
    __shared__ int    sidx[16 * 32];               // 2 KB
    __shared__ double ddL[16 * 32];                // 4 KB
    const int id  = blockIdx.x;                    // 2048, XCD-pinned
    const int xcd = id & 7, qq = id >> 3;          // qq 0..255
    const int b   = xcd + ((qq >> 7) << 3);
    const int q0  = (qq & 127) * 16;
    const int t = threadIdx.x;
    const float* xTb = xT + (size_t)b * NPT * CIN;
    #pragma unroll
    for (int e = 0; e < 2; ++e)                    // 512 survivor ids
        sidx[e * 256 + t] = surv[((size_t)b * NPT + q0) * SIFT + e * 256 + t];
    #pragma unroll
    for (int e = 0; e < 2; ++e) {                  // 16 q-rows, coalesced
        int f = e * 256 + t;
        int row = f >> 5, c4 = (f & 31) << 2;
        *(float4*)&Qs[row * 128 + c4] = *(const float4*)&xTb[(size_t)(q0 + row) * CIN + c4];
    }
    __syncthreads();
    const int g = t >> 3, j = t & 7;               // 32 groups x 8 lanes
    #pragma unroll 1
    for (int it = 0; it < 16; ++it) {              // 512 pairs per block
        int pair = it * 32 + g;
        int q = pair >> 5, k = pair & 31;
        int m = sidx[q * 32 + k];
        const float* mrow = xTb + (size_t)m * CIN + j * 16;
        const float* qrow = Qs + q * 128 + j * 16;
        float4 a0 = *(const float4*)&mrow[0];
        float4 a1 = *(const float4*)&mrow[4];
        float4 a2 = *(const float4*)&mrow[8];
        float4 a3 = *(const float4*)&mrow[12];
        float4 c0 = *(const float4*)&qrow[0];
        float4 c1 = *(const float4*)&qrow[4];
        float4 c2 = *(const float4*)&qrow[8];
        float4 c3 = *(const float4*)&qrow[12];
        double ss = 0.0, d0;
        d0 = (double)c0.x - (double)a0.x; ss = fma(d0, d0, ss);
        d0 = (double)c0.y - (double)a0.y; ss = fma(d0, d0, ss);
        d0 = (double)c0.z - (double)a0.z; ss = fma(d0, d0, ss);
        d0 = (double)c0.w - (double)a0.w; ss = fma(d0, d0, ss);
        d0 = (double)c1.x - (double)a1.x; ss = fma(d0, d0, ss);
        d0 = (double)c1.y - (double)a1.y; ss = fma(d0, d0, ss);
        d0 = (double)c1.z - (double)a1.z; ss = fma(d0, d0, ss);
        d0 = (double)c1.w - (double)a1.w; ss = fma(d0, d0, ss);
        d0 = (double)c2.x - (double)a2.x; ss = fma(d0, d0, ss);
        d0 = (double)c2.y - (double)a2.y; ss = fma(d0, d0, ss);
        d0 = (double)c2.z - (double)a2.z; ss = fma(d0, d0, ss);
        d0 = (double)c2.w - (double)a2.w; ss = fma(d0, d0, ss);
        d0 = (double)c3.x - (double)a3.x; ss = fma(d0, d0, ss);
        d0 = (double)c3.y - (double)a3.y; ss = fma(d0, d0, ss);
        d0 = (double)c3.z - (double)a3.z; ss = fma(d0, d0, ss);
        d0 = (double)c3.w - (double)a3.w; ss = fma(d0, d0, ss);
        ss += __shfl_xor(ss, 1, 8);                // butterfly within group
        ss += __shfl_xor(ss, 2, 8);
        ss += __shfl_xor(ss, 4, 8);
        if (j == 0) ddL[q * 32 + k] = ss;
    }
    __syncthreads();
    // exact parallel selection: rank-count over the 32 refined per query
    const int q = t >> 4, kk = (t & 15) << 1;
    int* dst = knn_out + ((size_t)b * NPT + q0 + q) * KNN;
    #pragma unroll
    for (int e = 0; e < 2; ++e) {
        int k = kk + e;
        double mine = ddL[q * 32 + k];
        int c = 0;
        #pragma unroll 4
        for (int jx = 0; jx < SIFT; ++jx)
            c += (ddL[q * 32 + jx] < mine) ? 1 : 0;
        if (c < KNN) dst[c] = sidx[q * 32 + k];
    }
}

// ------------------------------------------------- fallback single-kernel KNN
__global__ __launch_bounds__(256, 2) void knn_kernel_fb(const _Float16* __restrict__ xhT,
                                                        const float* __restrict__ xT,
                                                        const float* __restrict__ sqh,
                                                        int* __restrict__ knn_out) {
    __shared__ char smraw[59392];
    _Float16* bufA = (_Float16*)smraw;
    float*    sqm  = (float*)(smraw + 18432);

    const int b  = blockIdx.y;
    const int q0 = blockIdx.x * 64;
    const int t  = threadIdx.x;
    const int lane = t & 63, wv = t >> 6;
    const int l15 = lane & 15, quad = lane >> 4;
    const _Float16* xhb = xhT + (size_t)b * NPT * CIN;

    #pragma unroll
    for (int e = 0; e < 8; ++e)
        sqm[e * 256 + t] = sqh[b * NPT + e * 256 + t] + DBIAS;

    stage_pts(xhb, bufA, q0, t);
    __syncthreads();

    f16x8 af[4][4];
    #pragma unroll
    for (int qh = 0; qh < 4; ++qh)
        #pragma unroll
        for (int ks = 0; ks < 4; ++ks)
            af[qh][ks] = *(const f16x8*)(bufA + (size_t)((qh * 4 + ks) * 64 + lane) * 8);
    __syncthreads();

    _Float16* wbuf = (_Float16*)(smraw + 26624 + wv * 8192);
    float*    DtW  = (float*)(smraw + wv * 4608);
    const _Float16* srcl = xhb + (size_t)(wv * 16 + l15) * CIN + quad * 8;
    stage_tile16(srcl, wbuf);

    float bd[KEEP];
    #pragma unroll
    for (int i = 0; i < KEEP; ++i) bd[i] = 3.0e38f;

    #pragma unroll 1
    for (int ss = 0; ss < 32; ++ss) {
        const int mb = ss * 64 + wv * 16;
        asm volatile("s_waitcnt vmcnt(0)" ::: "memory");
        __builtin_amdgcn_sched_barrier(0);
        const _Float16* cur = wbuf + (ss & 1) * 2048;
        f16x8 bf[4];
        #pragma unroll
        for (int ks = 0; ks < 4; ++ks)
            bf[ks] = *(const f16x8*)(cur + ks * 512 + lane * 8);
        float sm_ = sqm[mb + l15];
        asm volatile("s_waitcnt lgkmcnt(0)" ::: "memory");
        __builtin_amdgcn_sched_barrier(0);
        if (ss < 31)
            stage_tile16(srcl + (size_t)(ss + 1) * 64 * CIN,
                         wbuf + ((ss + 1) & 1) * 2048);
        __builtin_amdgcn_sched_barrier(0);
        f32x4 acc[4];
        #pragma unroll
        for (int qh = 0; qh < 4; ++qh) acc[qh] = (f32x4){0.f, 0.f, 0.f, 0.f};
        #pragma unroll
        for (int ks = 0; ks < 4; ++ks)
            #pragma unroll
            for (int qh = 0; qh < 4; ++qh)
                acc[qh] = __builtin_amdgcn_mfma_f32_16x16x32_f16(af[qh][ks], bf[ks], acc[qh], 0, 0, 0);
        const unsigned om = (unsigned)(mb + l15);
        #pragma unroll
        for (int qh = 0; qh < 4; ++qh) {
            #pragma unroll
            for (int rg = 0; rg < 4; ++rg) {
                int q = qh * 16 + quad * 4 + rg;
                float d = sm_ - 2.f * acc[qh][rg];
                DtW[q * 18 + l15] = __uint_as_float((__float_as_uint(d) & 0xFFFFF800u) | om);
            }
        }
        float nk[16];
        {
            const float* myrow = DtW + lane * 18;
            #pragma unroll
            for (int p = 0; p < 8; ++p) {
                f32x2 v = *(const f32x2*)(myrow + 2 * p);
                nk[2 * p] = v[0]; nk[2 * p + 1] = v[1];
            }
        }
        #pragma unroll
        for (int kk = 2; kk <= 16; kk <<= 1) {
            #pragma unroll
            for (int j = kk >> 1; j > 0; j >>= 1) {
                #pragma unroll
                for (int i = 0; i < 16; ++i) {
                    int p = i ^ j;
                    if (p > i) {
                        float a = nk[i], c = nk[p];
                        float lo = fminf(a, c), hi = fmaxf(a, c);
                        if ((i & kk) == 0) { nk[i] = lo; nk[p] = hi; }
                        else               { nk[i] = hi; nk[p] = lo; }
                    }
                }
            }
        }
        #pragma unroll
        for (int i = 0; i < 16; ++i) bd[i] = fminf(bd[i], nk[15 - i]);
        #pragma unroll
        for (int j = 8; j > 0; j >>= 1) {
            #pragma unroll
            for (int i = 0; i < 16; ++i) {
                int p = i ^ j;
                if (p > i) {
                    float a = bd[i], c = bd[p];
                    bd[i] = fminf(a, c);
                    bd[p] = fmaxf(a, c);
                }
            }
        }
    }

    __syncthreads();

    float*  Keys = (float*)smraw;
    int*    Surv = (int*)(smraw + 16640);
    double* ddL  = (double*)(smraw + 25088);
    #pragma unroll
    for (int i = 0; i < KEEP; ++i)
        Keys[lane * 65 + wv * KEEP + i] = bd[i];
    __syncthreads();
    {
        int cnt[KEEP];
        #pragma unroll
        for (int i = 0; i < KEEP; ++i) cnt[i] = 0;
        #pragma unroll 4
        for (int j = 0; j < 64; ++j) {
            float kj = Keys[lane * 65 + j];
            #pragma unroll
            for (int i = 0; i < KEEP; ++i)
                cnt[i] += (kj < bd[i]) ? 1 : 0;
        }
        __syncthreads();
        #pragma unroll
        for (int i = 0; i < KEEP; ++i)
            if (cnt[i] < SIFT)
                Surv[lane * 33 + cnt[i]] = (int)(__float_as_uint(bd[i]) & 0x7FFu);
    }
    __syncthreads();

    int ms[8];
    #pragma unroll
    for (int k = 0; k < 8; ++k) ms[k] = Surv[lane * 33 + wv * 8 + k] & 2047;
    double dd8[8];
    #pragma unroll
    for (int k = 0; k < 8; ++k) dd8[k] = 0.0;
    const float* xTb = xT + (size_t)b * NPT * CIN;
    const float* qrow = xTb + (size_t)(q0 + lane) * CIN;
    #pragma unroll 1
    for (int ch = 0; ch < 8; ++ch) {
        double qd[16];
        #pragma unroll
        for (int j = 0; j < 4; ++j) {
            float4 qv = *(const float4*)&qrow[ch * 16 + 4 * j];
            qd[4 * j] = (double)qv.x; qd[4 * j + 1] = (double)qv.y;
            qd[4 * j + 2] = (double)qv.z; qd[4 * j + 3] = (double)qv.w;
        }
        #pragma unroll
        for (int k = 0; k < 8; ++k) {
            const float* mrow = xTb + (size_t)ms[k] * CIN + ch * 16;
            float4 ma = *(const float4*)&mrow[0];
            float4 mb2 = *(const float4*)&mrow[4];
            float4 mc = *(const float4*)&mrow[8];
            float4 md = *(const float4*)&mrow[12];
            double ss = dd8[k], d0;
            d0 = qd[0]  - (double)ma.x;  ss = fma(d0, d0, ss);
            d0 = qd[1]  - (double)ma.y;  ss = fma(d0, d0, ss);
            d0 = qd[2]  - (double)ma.z;  ss = fma(d0, d0, ss);
            d0 = qd[3]  - (double)ma.w;  ss = fma(d0, d0, ss);
            d0 = qd[4]  - (double)mb2.x; ss = fma(d0, d0, ss);
            d0 = qd[5]  - (double)mb2.y; ss = fma(d0, d0, ss);
            d0 = qd[6]  - (double)mb2.z; ss = fma(d0, d0, ss);
            d0 = qd[7]  - (double)mb2.w; ss = fma(d0, d0, ss);
            d0 = qd[8]  - (double)mc.x;  ss = fma(d0, d0, ss);
            d0 = qd[9]  - (double)mc.y;  ss = fma(d0, d0, ss);
            d0 = qd[10] - (double)mc.z;  ss = fma(d0, d0, ss);
            d0 = qd[11] - (double)mc.w;  ss = fma(d0, d0, ss);
            d0 = qd[12] - (double)md.x;  ss = fma(d0, d0, ss);
            d0 = qd[13] - (double)md.y;  ss = fma(d0, d0, ss);
            d0 = qd[14] - (double)md.z;  ss = fma(d0, d0, ss);
            d0 = qd[15] - (double)md.w;  ss = fma(d0, d0, ss);
            dd8[k] = ss;
        }
    }
    #pragma unroll
    for (int k = 0; k < 8; ++k) ddL[lane * 33 + wv * 8 + k] = dd8[k];
    __syncthreads();
    int* dst = knn_out + ((size_t)b * NPT + q0 + lane) * KNN;
    #pragma unroll
    for (int k = 0; k < 8; ++k) {
        int c = 0;
        #pragma unroll 4
        for (int j = 0; j < SIFT; ++j)
            c += (ddL[lane * 33 + j] < dd8[k]) ? 1 : 0;
        if (c < KNN) dst[c] = ms[k];
    }
}

// ------------------------------------------------- legacy fp32 u/v GEMM (fallback)
__global__ __launch_bounds__(256) void uv_gemm(const float* __restrict__ x,
                                               const float* __restrict__ W,
                                               float* __restrict__ uT,
                                               float* __restrict__ vT) {
    __shared__ float Ax[32 * 64];
    __shared__ float Bu[32 * 68];
    __shared__ float Bv[32 * 68];
    const int b  = blockIdx.z;
    const int n0 = blockIdx.x * 64;
    const int o0 = blockIdx.y * 64;
    const int t  = threadIdx.x;
    const int tx = t & 15, ty = t >> 4;
    const float* xb = x + (size_t)b * CIN * NPT;
    float au[4][4], av_[4][4];
    #pragma unroll
    for (int i = 0; i < 4; ++i)
        #pragma unroll
        for (int j = 0; j < 4; ++j) { au[i][j] = 0.f; av_[i][j] = 0.f; }
    #pragma unroll 1
    for (int kc = 0; kc < 4; ++kc) {
        const int c0 = kc * 32;
        __syncthreads();
        #pragma unroll
        for (int e = 0; e < 2; ++e) {
            int f = e * 256 + t;
            int cz = f >> 4, ni = (f & 15) << 2;
            *(float4*)&Ax[(cz << 6) + ni] = *(const float4*)&xb[(size_t)(c0 + cz) * NPT + n0 + ni];
        }
        #pragma unroll
        for (int e = 0; e < 8; ++e) {
            int ii = e * 256 + t;
            int cz = ii & 31, oj = ii >> 5;
            float w1 = W[(size_t)(o0 + oj) * 256 + c0 + cz];
            float w2 = W[(size_t)(o0 + oj) * 256 + 128 + c0 + cz];
            Bu[cz * 68 + oj] = w1 - w2;
            Bv[cz * 68 + oj] = w2;
        }
        __syncthreads();
        #pragma unroll 8
        for (int cz = 0; cz < 32; ++cz) {
            const float4 a4 = *(const float4*)&Ax[(cz << 6) + (tx << 2)];
            float bu0 = Bu[cz * 68 + (ty << 2) + 0], bv0 = Bv[cz * 68 + (ty << 2) + 0];
            float bu1 = Bu[cz * 68 + (ty << 2) + 1], bv1 = Bv[cz * 68 + (ty << 2) + 1];
            float bu2 = Bu[cz * 68 + (ty << 2) + 2], bv2 = Bv[cz * 68 + (ty << 2) + 2];
            float bu3 = Bu[cz * 68 + (ty << 2) + 3], bv3 = Bv[cz * 68 + (ty << 2) + 3];
            au[0][0] += a4.x * bu0; au[0][1] += a4.x * bu1; au[0][2] += a4.x * bu2; au[0][3] += a4.x * bu3;
            au[1][0] += a4.y * bu0; au[1][1] += a4.y * bu1; au[1][2] += a4.y * bu2; au[1][3] += a4.y * bu3;
            au[2][0] += a4.z * bu0; au[2][1] += a4.z * bu1; au[2][2] += a4.z * bu2; au[2][3] += a4.z * bu3;
            au[3][0] += a4.w * bu0; au[3][1] += a4.w * bu1; au[3][2] += a4.w * bu2; au[3][3] += a4.w * bu3;
            av_[0][0] += a4.x * bv0; av_[0][1] += a4.x * bv1; av_[0][2] += a4.x * bv2; av_[0][3] += a4.x * bv3;
            av_[1][0] += a4.y * bv0; av_[1][1] += a4.y * bv1; av_[1][2] += a4.y * bv2; av_[1][3] += a4.y * bv3;
            av_[2][0] += a4.z * bv0; av_[2][1] += a4.z * bv1; av_[2][2] += a4.z * bv2; av_[2][3] += a4.z * bv3;
            av_[3][0] += a4.w * bv0; av_[3][1] += a4.w * bv1; av_[3][2] += a4.w * bv2; av_[3][3] += a4.w * bv3;
        }
    }
    #pragma unroll
    for (int i = 0; i < 4; ++i) {
        int n = n0 + (tx << 2) + i;
        size_t base = ((size_t)b * NPT + n) * COUT + o0 + (ty << 2);
        float4 u4 = {au[i][0], au[i][1], au[i][2], au[i][3]};
        float4 v4 = {av_[i][0], av_[i][1], av_[i][2], av_[i][3]};
        *(float4*)&uT[base] = u4;
        *(float4*)&vT[base] = v4;
    }
}

// ------------------------------------------------- fused gather+stats (pass A)
// 2048 blocks XCD-pinned (fp16 vT slice = 1 MB/batch, 2 MB/XCD in L2).
// fp16 u/v in, fp32 compute, fp16 y1/y2 out (nontemporal). BN sums in double.
__global__ __launch_bounds__(256) void gather_stats(const _Float16* __restrict__ uT,
                                                    const _Float16* __restrict__ vT,
                                                    const int* __restrict__ knn_in,
                                                    double* __restrict__ gsum,
                                                    _Float16* __restrict__ aMax,
                                                    _Float16* __restrict__ aMin) {
    __shared__ int sidx[16 * KNN];
    const int id  = blockIdx.x;                    // 2048, XCD-pinned
    const int xcd = id & 7, qq = id >> 3;          // qq 0..255
    const int b   = xcd + ((qq >> 7) << 3);
    const int inner = qq & 127;
    const int n0  = (inner >> 2) * 64 + (inner & 3) * 16;
    const int o   = threadIdx.x;
    for (int e = o; e < 16 * KNN; e += 256)
        sidx[e] = knn_in[((size_t)b * NPT + n0) * KNN + e];
    __syncthreads();
    const _Float16* ub = uT + ((size_t)b * NPT + n0) * COUT + o;
    const _Float16* vb = vT + (size_t)b * NPT * COUT + o;
    _Float16* amx = aMax + ((size_t)b * NPT + n0) * COUT + o;
    _Float16* amn = aMin + ((size_t)b * NPT + n0) * COUT + o;
    double s1 = 0.0, s2 = 0.0;
    #pragma unroll 1
    for (int s = 0; s < 16; ++s) {
        float u = (float)ub[(size_t)s * COUT];
        float vmax = -3e38f, vmin = 3e38f, vsum = 0.f, vsq = 0.f;
        #pragma unroll
        for (int j = 0; j < KNN; ++j) {
            float v = (float)vb[(size_t)sidx[s * KNN + j] * COUT];
            vmax = fmaxf(vmax, v);
            vmin = fminf(vmin, v);
            vsum += v;
            vsq = fmaf(v, v, vsq);
        }
        s1 += 20.0 * (double)u + (double)vsum;
        s2 += 20.0 * (double)u * (double)u + 2.0 * (double)u * (double)vsum + (double)vsq;
        _Float16 y1 = (_Float16)(u + vmax);        // == max_j (u+v_j), RN monotone
        _Float16 y2 = (_Float16)(u + vmin);
        __builtin_nontemporal_store(y1, &amx[(size_t)s * COUT]);
        __builtin_nontemporal_store(y2, &amn[(size_t)s * COUT]);
    }
    atomicAdd(&gsum[o], s1);
    atomicAdd(&gsum[COUT + o], s2);
}

// ------------------------------------------------- BN statistics (legacy pass A)
__global__ __launch_bounds__(256) void stats_kernel(const float* __restrict__ uT,
                                                    const float* __restrict__ vT,
                                                    const int* __restrict__ knn_in,
                                                    double* __restrict__ gsum) {
    __shared__ int sidx[64 * KNN];
    const int b  = blockIdx.y;
    const int n0 = blockIdx.x * 64;
    const int o  = threadIdx.x;
    for (int e = o; e < 64 * KNN; e += 256)
        sidx[e] = knn_in[((size_t)b * NPT + n0) * KNN + e];
    __syncthreads();
    const float* ub = uT + ((size_t)b * NPT + n0) * COUT + o;
    const float* vb = vT + (size_t)b * NPT * COUT + o;
    double s1 = 0.0, s2 = 0.0;
    #pragma unroll 1
    for (int s = 0; s < 64; ++s) {
        float u = ub[(size_t)s * COUT];
        #pragma unroll
        for (int j = 0; j < KNN; ++j) {
            float y = u + vb[(size_t)sidx[s * KNN + j] * COUT];
            s1 += (double)y;
            s2 = fma((double)y, (double)y, s2);
        }
    }
    atomicAdd(&gsum[o], s1);
    atomicAdd(&gsum[COUT + o], s2);
}

// ------------------------------------------------- fold stats -> scale/shift
__global__ void finalize_kernel(const double* __restrict__ gsum,
                                const float* __restrict__ gamma,
                                const float* __restrict__ beta,
                                float* __restrict__ st) {
    const int o = threadIdx.x;
    const double M = (double)B_ * NPT * KNN;
    double mean = gsum[o] / M;
    double var  = gsum[COUT + o] / M - mean * mean;
    float inv = 1.0f / sqrtf((float)var + EPS);
    float s = gamma[o] * inv;
    st[o] = s;
    st[COUT + o] = beta[o] - (float)mean * s;
}

// ------------------------------------------------- out from fp16 y1/y2 (fused)
// 1D 512-block grid, XCD-pinned; folds finalize in (each thread derives
// s/tt from gsum directly -- stream order guarantees atomics complete).
__global__ __launch_bounds__(256, 2) void out2_kernel(const _Float16* __restrict__ aMax,
                                                      const _Float16* __restrict__ aMin,
                                                      const double* __restrict__ gsum,
                                                      const float* __restrict__ gamma,
                                                      const float* __restrict__ beta,
                                                      float* __restrict__ out) {
    __shared__ float zt[256 * 68];
    const int id  = blockIdx.x;                    // 512, XCD-pinned
    const int xcd = id & 7, qq = id >> 3;          // qq 0..63
    const int b   = xcd + ((qq >> 5) << 3);
    const int n0  = (qq & 31) * 64;
    const int o = threadIdx.x;
    const double M = (double)B_ * NPT * KNN;
    double mean = gsum[o] / M;
    double var  = gsum[COUT + o] / M - mean * mean;
    float inv = 1.0f / sqrtf((float)var + EPS);
    const float s  = gamma[o] * inv;
    const float tt = beta[o] - (float)mean * s;
    const _Float16* amx = aMax + ((size_t)b * NPT + n0) * COUT + o;
    const _Float16* amn = aMin + ((size_t)b * NPT + n0) * COUT + o;
    #pragma unroll 2
    for (int si = 0; si < 64; ++si) {
        float y1 = (float)amx[(size_t)si * COUT];
        float y2 = (float)amn[(size_t)si * COUT];
        float z1 = fmaxf(s * y1 + tt, 0.f);
        float z2 = fmaxf(s * y2 + tt, 0.f);
        zt[o * 68 + si] = fmaxf(z1, z2);
    }
    __syncthreads();
    float* dst = out + ((size_t)b * COUT + o) * NPT + n0;
    #pragma unroll
    for (int i = 0; i < 16; ++i)
        *(float4*)&dst[i * 4] = *(const float4*)&zt[o * 68 + i * 4];
}

// ------------------------------------------------- legacy gather+affine+relu+max
__global__ __launch_bounds__(256, 2) void out_kernel(const float* __restrict__ uT,
                                                     const float* __restrict__ vT,
                                                     const int* __restrict__ knn_in,
                                                     const float* __restrict__ st,
                                                     float* __restrict__ out) {
    __shared__ int sidx[64 * KNN];
    __shared__ float zt[256 * 68];
    const int b  = blockIdx.y;
    const int n0 = blockIdx.x * 64;
    const int o  = threadIdx.x;
    for (int e = o; e < 64 * KNN; e += 256)
        sidx[e] = knn_in[((size_t)b * NPT + n0) * KNN + e];
    __syncthreads();
    const float s  = st[o];
    const float tt = st[COUT + o];
    const float* ub = uT + ((size_t)b * NPT + n0) * COUT + o;
    const float* vb = vT + (size_t)b * NPT * COUT + o;
    #pragma unroll 1
    for (int si = 0; si < 64; ++si) {
        float u = ub[(size_t)si * COUT];
        float ymax = -3e38f, ymin = 3e38f;
        #pragma unroll
        for (int j = 0; j < KNN; ++j) {
            float y = u + vb[(size_t)sidx[si * KNN + j] * COUT];
            ymax = fmaxf(ymax, y);
            ymin = fminf(ymin, y);
        }
        float z1 = fmaxf(s * ymax + tt, 0.f);
        float z2 = fmaxf(s * ymin + tt, 0.f);
        zt[o * 68 + si] = fmaxf(z1, z2);
    }
    __syncthreads();
    float* dst = out + ((size_t)b * COUT + o) * NPT + n0;
    #pragma unroll
    for (int i = 0; i < 16; ++i)
        *(float4*)&dst[i * 4] = *(const float4*)&zt[o * 68 + i * 4];
}

extern "C" void kernel_launch(void* const* d_in, const int* in_sizes, int n_in,
                              void* d_out, int out_size, void* d_ws, size_t ws_size,
                              hipStream_t stream) {
    const float* x     = (const float*)d_in[0];
    const float* W     = (const float*)d_in[1];
    const float* gamma = (const float*)d_in[2];
    const float* beta  = (const float*)d_in[3];
    float* out = (float*)d_out;
    char* ws = (char*)d_ws;
    float*     sqh  = (float*)(ws + SQ_OFF);
    int*       idx  = (int*)(ws + IDX_OFF);
    double*    gsum = (double*)(ws + GS_OFF);
    float*     st   = (float*)(ws + ST_OFF);
    const bool fused = (ws_size >= WS_NEED_FUSED);

    if (fused) {
        // xT (fp32) + xhT (fp16) in the AMAX region (xT dead after refine;
        // fp16 aMax overwrites the xT slot). Survivor ids at AMIN_OFF (dead
        // until gather writes fp16 aMin). uT/vT fp16, written by fused prep.
        float*    xT   = (float*)(ws + AMAX_OFF);
        _Float16* xhT  = (_Float16*)(ws + AMAX_OFF + 16777216ull);
        int*      svG  = (int*)(ws + AMIN_OFF);
        _Float16* uTh  = (_Float16*)(ws + UT_OFF);
        _Float16* vTh  = (_Float16*)(ws + VT_OFF);
        _Float16* aMxh = (_Float16*)(ws + AMAX_OFF);
        _Float16* aMnh = (_Float16*)(ws + AMIN_OFF);
        prep_kernel<<<512, 256, 0, stream>>>(x, W, xT, xhT, sqh, uTh, vTh, gsum);
        knn_kernel<<<512, 256, 0, stream>>>(xhT, sqh, svG);
        refine_kernel<<<2048, 256, 0, stream>>>(xT, svG, idx);
        gather_stats<<<2048, 256, 0, stream>>>(uTh, vTh, idx, gsum, aMxh, aMnh);
        out2_kernel<<<512, 256, 0, stream>>>(aMxh, aMnh, gsum, gamma, beta, out);
    } else {
        // fallback: fp32 path; xT aliases uT, xhT aliases vT; fp32 uv after knn
        float*    xT  = (float*)(ws + XT_OFF);
        _Float16* xhT = (_Float16*)(ws + XHT_OFF);
        float*    uT  = (float*)(ws + UT_OFF);
        float*    vT  = (float*)(ws + VT_OFF);
        prep_kernel<<<512, 256, 0, stream>>>(x, W, xT, xhT, sqh, nullptr, nullptr, gsum);
        knn_kernel_fb<<<dim3(32, 16), 256, 0, stream>>>(xhT, xT, sqh, idx);
        uv_gemm<<<dim3(32, 4, 16), 256, 0, stream>>>(x, W, uT, vT);
        stats_kernel<<<dim3(32, 16), 256, 0, stream>>>(uT, vT, idx, gsum);
        finalize_kernel<<<1, 256, 0, stream>>>(gsum, gamma, beta, st);
        out_kernel<<<dim3(32, 16), 256, 0, stream>>>(uT, vT, idx, st, out);
    }
}

// Round 13
// 298.394 us; speedup vs baseline: 1.0730x; 1.0730x over previous
//
#include <hip/hip_runtime.h>

#define B_   16
#define CIN  128
#define NPT  2048
#define COUT 256
#define KNN  20
#define KEEP 16
#define SIFT 32
#define EPS  1e-5f
#define DBIAS 256.0f   // must exceed max_q |x_q|^2 (chi2_128 max ~210 over 32k)

// workspace byte offsets
#define SQ_OFF   0ull                          // sqh: 32768 f (fp16-rounded |x|^2)
#define IDX_OFF  131072ull                     // 16*2048*20 i32
#define UT_OFF   2752512ull                    // fp16 uT: 16*2048*256 h = 16.8M (fallback: f32)
#define VT_OFF   36306944ull                   // fp16 vT (fallback: f32)
#define GS_OFF   69861376ull                   // 2*256 double
#define ST_OFF   69865472ull                   // 2*256 f
// fused-path buffers (only when ws_size is large enough)
#define AMAX_OFF 69871616ull                   // fp16 aMax: 16.8M (region is 33.5M)
#define AMIN_OFF 103426048ull                  // fp16 aMin
#define WS_NEED_FUSED 136980480ull
// Fused mode: xT/xhT/Wu/Wv live in the AMAX region (dead until gather_stats
// writes aMax; fp16 aMax spans only [0,16.8M) = the xT slot, and xT is dead
// after refine). Survivor ids (4 MB) alias the uT region: written by knn,
// consumed by refine, then uv_gemm_h overwrites uT.
#define XT_OFF   UT_OFF
#define XHT_OFF  VT_OFF

typedef _Float16 f16x8 __attribute__((ext_vector_type(8)));
typedef _Float16 f16x4 __attribute__((ext_vector_type(4)));
typedef float    f32x4 __attribute__((ext_vector_type(4)));
typedef float    f32x2 __attribute__((ext_vector_type(2)));

// ---------------------------------------------------- prep: xT, xhT, sqh (+Wu/Wv)
// 1D 512-block grid, XCD-pinned with the SAME decode as knn/refine so the
// xhT/xT slices for batch b are written into the L2 of the XCD that will
// read them. Blocks 0..127 additionally fold in the W -> Wu/Wv conversion;
// block 0 zeroes gsum (replaces the hipMemsetAsync dispatch).
// NOTE (r12 lesson): do NOT fuse the u/v GEMM here -- the fat kernel hits
// the 64-VGPR allocator cliff and strided scalar LDS reads; the separate
// uv_gemm_h with global_load_lds staging is faster despite re-reading xhT.
__global__ __launch_bounds__(256) void prep_kernel(const float* __restrict__ x,
                                                   const float* __restrict__ W,
                                                   float* __restrict__ xT,
                                                   _Float16* __restrict__ xhT,
                                                   _Float16* __restrict__ Wu,
                                                   _Float16* __restrict__ Wv,
                                                   float* __restrict__ sqh,
                                                   double* __restrict__ gsum) {
    __shared__ float Ls[128 * 68];
    __shared__ float ps[4 * 64];
    const int id  = blockIdx.x;                // 512, XCD-pinned
    const int xcd = id & 7, qq = id >> 3;      // qq 0..63
    const int b   = xcd + ((qq >> 5) << 3);
    const int n0  = (qq & 31) * 64;
    const int t = threadIdx.x;
    if (id == 0) {                             // fold gsum zeroing (512 doubles)
        gsum[t] = 0.0;
        gsum[256 + t] = 0.0;
    }
    if (Wu != nullptr && id < 128) {           // fused W conversion (32768 elems)
        int gid = id * 256 + t;
        int o = gid >> 7, c = gid & 127;
        float w1 = W[o * 256 + c], w2 = W[o * 256 + 128 + c];
        Wu[gid] = (_Float16)(w1 - w2);
        Wv[gid] = (_Float16)w2;
    }
    const float* xb = x + (size_t)b * CIN * NPT;
    #pragma unroll
    for (int e = 0; e < 8; ++e) {              // 2048 float4 loads, coalesced
        int f = e * 256 + t;
        int c = f >> 4, n4 = (f & 15) << 2;
        *(float4*)&Ls[c * 68 + n4] = *(const float4*)&xb[(size_t)c * NPT + n0 + n4];
    }
    __syncthreads();
    {                                          // sq partials on fp16-rounded vals
        int nl = t & 63, part = t >> 6;
        float acc = 0.f;
        #pragma unroll
        for (int j = 0; j < 32; ++j) {
            float vh = (float)(_Float16)Ls[(part * 32 + j) * 68 + nl];
            acc += vh * vh;
        }
        ps[part * 64 + nl] = acc;
    }
    #pragma unroll
    for (int e = 0; e < 2; ++e) {              // transpose writes: (nl, 16-c chunk)
        int u = e * 256 + t;
        int nl = u >> 3, ck = (u & 7) << 4;
        float vv[16];
        #pragma unroll
        for (int j = 0; j < 16; ++j) vv[j] = Ls[(ck + j) * 68 + nl];
        size_t row = (size_t)b * NPT + n0 + nl;
        #pragma unroll
        for (int j = 0; j < 4; ++j) {
            float4 w = {vv[4 * j], vv[4 * j + 1], vv[4 * j + 2], vv[4 * j + 3]};
            *(float4*)&xT[row * CIN + ck + 4 * j] = w;
        }
        f16x8 h0, h1;
        #pragma unroll
        for (int j = 0; j < 8; ++j) { h0[j] = (_Float16)vv[j]; h1[j] = (_Float16)vv[8 + j]; }
        *(f16x8*)&xhT[row * CIN + ck] = h0;
        *(f16x8*)&xhT[row * CIN + ck + 8] = h1;
    }
    __syncthreads();
    if (t < 64) sqh[b * NPT + n0 + t] = ps[t] + ps[64 + t] + ps[128 + t] + ps[192 + t];
}

// -------------------------------------------- 64-row fragment staging via DMA
__device__ __forceinline__ void stage_pts(const _Float16* __restrict__ xhb,
                                          _Float16* buf, int base_n, int t) {
    const int l15 = t & 15, ks = t >> 6;
    const int quad = (t >> 4) & 3;
    const int c = ks * 32 + quad * 8;
    #pragma unroll
    for (int e = 0; e < 4; ++e) {
        const int n = base_n + e * 16 + l15;
        const _Float16* src = xhb + (size_t)n * CIN + c;
        _Float16* dst = buf + (size_t)(e * 256 + (t & 192)) * 8;   // wave-uniform base
        __builtin_amdgcn_global_load_lds(
            (const __attribute__((address_space(1))) void*)src,
            (__attribute__((address_space(3))) void*)dst, 16, 0, 0);
    }
}

// -------------------------------------------- per-wave 16-row tile staging
// srcl = per-lane ptr: row (m_base + lane&15), chan (lane>>4)*8.
// dst elem = e*512 + lane*8 holds (m = lane&15, chans (lane>>4)*8 + e*32 ..+8)
// -> B-fragment order bf[ks] = tile[ks*512 + lane*8].
__device__ __forceinline__ void stage_tile16(const _Float16* __restrict__ srcl,
                                             _Float16* dsthalf) {
    #pragma unroll
    for (int e = 0; e < 4; ++e) {
        __builtin_amdgcn_global_load_lds(
            (const __attribute__((address_space(1))) void*)(srcl + e * 32),
            (__attribute__((address_space(3))) void*)(dsthalf + (size_t)e * 512),
            16, 0, 0);
    }
}

// ---------------------------------------------------------------- KNN (split)
// ROUND-6 LOCKED CONFIG (measured ~72 us, VGPR 88): barrier-free main loop,
// 4-wave 256-thread blocks, 512 blocks XCD-pinned; each wave owns m-tiles
// (tile%4==wv) for ALL 64 queries; A-frags hoisted; per-wave double-buffered
// 16-m B tiles via global_load_lds; packed keys (21-bit chopped distance |
// 11-bit m) through wave-private Dt; thread=query batch-bitonic top-16.
// Tail stops after the quantized sift -> 32 survivor ids per query to global.
__global__ __launch_bounds__(256, 2) void knn_kernel(const _Float16* __restrict__ xhT,
                                                     const float* __restrict__ sqh,
                                                     int* __restrict__ surv_out) {
    __shared__ char smraw[59392];
    // [0,18432)      Dt: wave wv at wv*4608, [64 q][18 f] stride-18 rows
    //                (A-frag staging [0,16384) lives here before Dt starts)
    // [18432,26624)  sqm: 2048 f (biased +DBIAS)
    // [26624,59392)  per-wave B dbuf: wv at 26624+wv*8192, halves of 4096 B
    // tail aliases [0,16640): Keys
    _Float16* bufA = (_Float16*)smraw;
    float*    sqm  = (float*)(smraw + 18432);

    const int id  = blockIdx.x;                     // 512, XCD-pinned
    const int xcd = id & 7, qq = id >> 3;           // qq 0..63
    const int b   = xcd + ((qq >> 5) << 3);         // 2 batches per XCD
    const int q0  = (qq & 31) * 64;
    const int t  = threadIdx.x;
    const int lane = t & 63, wv = t >> 6;
    const int l15 = lane & 15, quad = lane >> 4;
    const _Float16* xhb = xhT + (size_t)b * NPT * CIN;

    #pragma unroll
    for (int e = 0; e < 8; ++e)
        sqm[e * 256 + t] = sqh[b * NPT + e * 256 + t] + DBIAS;

    stage_pts(xhb, bufA, q0, t);                    // A fragments (64 queries)
    __syncthreads();                                // A + sqm ready (drains vmcnt)

    f16x8 af[4][4];                                 // all 64 q in registers
    #pragma unroll
    for (int qh = 0; qh < 4; ++qh)
        #pragma unroll
        for (int ks = 0; ks < 4; ++ks)
            af[qh][ks] = *(const f16x8*)(bufA + (size_t)((qh * 4 + ks) * 64 + lane) * 8);
    __syncthreads();                                // A region free -> Dt may start

    _Float16* wbuf = (_Float16*)(smraw + 26624 + wv * 8192);
    float*    DtW  = (float*)(smraw + wv * 4608);
    const _Float16* srcl = xhb + (size_t)(wv * 16 + l15) * CIN + quad * 8;

    stage_tile16(srcl, wbuf);                       // step 0 -> half 0

    float bd[KEEP];
    #pragma unroll
    for (int i = 0; i < KEEP; ++i) bd[i] = 3.0e38f;

    #pragma unroll 1
    for (int ss = 0; ss < 32; ++ss) {
        const int mb = ss * 64 + wv * 16;           // this wave's tile base
        asm volatile("s_waitcnt vmcnt(0)" ::: "memory");   // cur half staged
        __builtin_amdgcn_sched_barrier(0);
        const _Float16* cur = wbuf + (ss & 1) * 2048;
        f16x8 bf[4];
        #pragma unroll
        for (int ks = 0; ks < 4; ++ks)
            bf[ks] = *(const f16x8*)(cur + ks * 512 + lane * 8);
        float sm_ = sqm[mb + l15];                  // = |xm|^2 + DBIAS
        asm volatile("s_waitcnt lgkmcnt(0)" ::: "memory");  // bf in regs
        __builtin_amdgcn_sched_barrier(0);
        if (ss < 31)                                // prefetch next tile
            stage_tile16(srcl + (size_t)(ss + 1) * 64 * CIN,
                         wbuf + ((ss + 1) & 1) * 2048);
        __builtin_amdgcn_sched_barrier(0);
        f32x4 acc[4];
        #pragma unroll
        for (int qh = 0; qh < 4; ++qh) acc[qh] = (f32x4){0.f, 0.f, 0.f, 0.f};
        #pragma unroll
        for (int ks = 0; ks < 4; ++ks)
            #pragma unroll
            for (int qh = 0; qh < 4; ++qh)
                acc[qh] = __builtin_amdgcn_mfma_f32_16x16x32_f16(af[qh][ks], bf[ks], acc[qh], 0, 0, 0);
        // pack keys (unique: chopped distance | full m), wave-private Dt
        const unsigned om = (unsigned)(mb + l15);
        #pragma unroll
        for (int qh = 0; qh < 4; ++qh) {
            #pragma unroll
            for (int rg = 0; rg < 4; ++rg) {        // D row = q (A free dim)
                int q = qh * 16 + quad * 4 + rg;
                float d = sm_ - 2.f * acc[qh][rg];
                DtW[q * 18 + l15] = __uint_as_float((__float_as_uint(d) & 0xFFFFF800u) | om);
            }
        }
        // read own query row (16 keys) -- same wave wrote it; in-order DS
        float nk[16];
        {
            const float* myrow = DtW + lane * 18;
            #pragma unroll
            for (int p = 0; p < 8; ++p) {
                f32x2 v = *(const f32x2*)(myrow + 2 * p);
                nk[2 * p] = v[0]; nk[2 * p + 1] = v[1];
            }
        }
        // bitonic sort nk ascending (keys > 0: float order == uint order)
        #pragma unroll
        for (int kk = 2; kk <= 16; kk <<= 1) {
            #pragma unroll
            for (int j = kk >> 1; j > 0; j >>= 1) {
                #pragma unroll
                for (int i = 0; i < 16; ++i) {
                    int p = i ^ j;
                    if (p > i) {
                        float a = nk[i], c = nk[p];
                        float lo = fminf(a, c), hi = fmaxf(a, c);
                        if ((i & kk) == 0) { nk[i] = lo; nk[p] = hi; }
                        else               { nk[i] = hi; nk[p] = lo; }
                    }
                }
            }
        }
        // bottom-16 of (bd ∪ nk): min(asc bd, desc nk) is bitonic, then clean
        #pragma unroll
        for (int i = 0; i < 16; ++i) bd[i] = fminf(bd[i], nk[15 - i]);
        #pragma unroll
        for (int j = 8; j > 0; j >>= 1) {
            #pragma unroll
            for (int i = 0; i < 16; ++i) {
                int p = i ^ j;
                if (p > i) {
                    float a = bd[i], c = bd[p];
                    bd[i] = fminf(a, c);
                    bd[p] = fmaxf(a, c);
                }
            }
        }
        // bd stays sorted ascending across steps
    }

    __syncthreads();                               // all waves done; alias smraw

    // ---- quantized pre-sift: rank-count the 64 packed keys per query ----
    // thread (wv, lane) holds subset-wv's top-16 for query q0+lane.
    float* Keys = (float*)smraw;                   // [64][65] f = 16640 B
    #pragma unroll
    for (int i = 0; i < KEEP; ++i)
        Keys[lane * 65 + wv * KEEP + i] = bd[i];
    __syncthreads();
    {
        int cnt[KEEP];
        #pragma unroll
        for (int i = 0; i < KEEP; ++i) cnt[i] = 0;
        #pragma unroll 4
        for (int j = 0; j < 64; ++j) {
            float kj = Keys[lane * 65 + j];
            #pragma unroll
            for (int i = 0; i < KEEP; ++i)
                cnt[i] += (kj < bd[i]) ? 1 : 0;
        }
        // ranks are unique (keys unique) -> exactly 32 survivors per query
        int* dst = surv_out + ((size_t)b * NPT + q0 + lane) * SIFT;
        #pragma unroll
        for (int i = 0; i < KEEP; ++i)
            if (cnt[i] < SIFT)
                dst[cnt[i]] = (int)(__float_as_uint(bd[i]) & 0x7FFu);
    }
}

// ---------------------------------------------------------------- refine
// Exact fp64 refinement. 2048 blocks, XCD-pinned (2 xT slices per XCD,
// L2-resident). 8-lane groups process one (q, survivor) pair; lane j covers
// dims [16j,16j+16) -> contiguous 512 B group read. Q-rows cached in LDS.
__global__ __launch_bounds__(256, 4) void refine_kernel(const float* __restrict__ xT,
                                                        const int* __restrict__ surv,
                                                        int* __restrict__ knn_out) {
    __shared__ float  Qs[16 * 128];                // 8 KB
    __shared__ int    sidx[16 * 32];               // 2 KB
    __shared__ double ddL[16 * 32];                // 4 KB
    const int id  = blockIdx.x;                    // 2048, XCD-pinned
    const int xcd = id & 7, qq = id >> 3;          // qq 0..255
    const int b   = xcd + ((qq >> 7) << 3);
    const int q0  = (qq & 127) * 16;
    const int t = threadIdx.x;
    const float* xTb = xT + (size_t)b * NPT * CIN;
    #pragma unroll
    for (int e = 0; e < 2; ++e)                    // 512 survivor ids
        sidx[e * 256 + t] = surv[((size_t)b * NPT + q0) * SIFT + e * 256 + t];
    #pragma unroll
    for (int e = 0; e < 2; ++e) {                  // 16 q-rows, coalesced
        int f = e * 256 + t;
        int row = f >> 5, c4 = (f & 31) << 2;
        *(float4*)&Qs[row * 128 + c4] = *(const float4*)&xTb[(size_t)(q0 + row) * CIN + c4];
    }
    __syncthreads();
    const int g = t >> 3, j = t & 7;               // 32 groups x 8 lanes
    #pragma unroll 1
    for (int it = 0; it < 16; ++it) {              // 512 pairs per block
        int pair = it * 32 + g;
        int q = pair >> 5, k = pair & 31;
        int m = sidx[q * 32 + k];
        const float* mrow = xTb + (size_t)m * CIN + j * 16;
        const float* qrow = Qs + q * 128 + j * 16;
        float4 a0 = *(const float4*)&mrow[0];
        float4 a1 = *(const float4*)&mrow[4];
        float4 a2 = *(const float4*)&mrow[8];
        float4 a3 = *(const float4*)&mrow[12];
        float4 c0 = *(const float4*)&qrow[0];
        float4 c1 = *(const float4*)&qrow[4];
        float4 c2 = *(const float4*)&qrow[8];
        float4 c3 = *(const float4*)&qrow[12];
        double ss = 0.0, d0;
        d0 = (double)c0.x - (double)a0.x; ss = fma(d0, d0, ss);
        d0 = (double)c0.y - (double)a0.y; ss = fma(d0, d0, ss);
        d0 = (double)c0.z - (double)a0.z; ss = fma(d0, d0, ss);
        d0 = (double)c0.w - (double)a0.w; ss = fma(d0, d0, ss);
        d0 = (double)c1.x - (double)a1.x; ss = fma(d0, d0, ss);
        d0 = (double)c1.y - (double)a1.y; ss = fma(d0, d0, ss);
        d0 = (double)c1.z - (double)a1.z; ss = fma(d0, d0, ss);
        d0 = (double)c1.w - (double)a1.w; ss = fma(d0, d0, ss);
        d0 = (double)c2.x - (double)a2.x; ss = fma(d0, d0, ss);
        d0 = (double)c2.y - (double)a2.y; ss = fma(d0, d0, ss);
        d0 = (double)c2.z - (double)a2.z; ss = fma(d0, d0, ss);
        d0 = (double)c2.w - (double)a2.w; ss = fma(d0, d0, ss);
        d0 = (double)c3.x - (double)a3.x; ss = fma(d0, d0, ss);
        d0 = (double)c3.y - (double)a3.y; ss = fma(d0, d0, ss);
        d0 = (double)c3.z - (double)a3.z; ss = fma(d0, d0, ss);
        d0 = (double)c3.w - (double)a3.w; ss = fma(d0, d0, ss);
        ss += __shfl_xor(ss, 1, 8);                // butterfly within group
        ss += __shfl_xor(ss, 2, 8);
        ss += __shfl_xor(ss, 4, 8);
        if (j == 0) ddL[q * 32 + k] = ss;
    }
    __syncthreads();
    // exact parallel selection: rank-count over the 32 refined per query
    const int q = t >> 4, kk = (t & 15) << 1;
    int* dst = knn_out + ((size_t)b * NPT + q0 + q) * KNN;
    #pragma unroll
    for (int e = 0; e < 2; ++e) {
        int k = kk + e;
        double mine = ddL[q * 32 + k];
        int c = 0;
        #pragma unroll 4
        for (int jx = 0; jx < SIFT; ++jx)
            c += (ddL[q * 32 + jx] < mine) ? 1 : 0;
        if (c < KNN) dst[c] = sidx[q * 32 + k];
    }
}

// ------------------------------------------------- fallback single-kernel KNN
__global__ __launch_bounds__(256, 2) void knn_kernel_fb(const _Float16* __restrict__ xhT,
                                                        const float* __restrict__ xT,
                                                        const float* __restrict__ sqh,
                                                        int* __restrict__ knn_out) {
    __shared__ char smraw[59392];
    _Float16* bufA = (_Float16*)smraw;
    float*    sqm  = (float*)(smraw + 18432);

    const int b  = blockIdx.y;
    const int q0 = blockIdx.x * 64;
    const int t  = threadIdx.x;
    const int lane = t & 63, wv = t >> 6;
    const int l15 = lane & 15, quad = lane >> 4;
    const _Float16* xhb = xhT + (size_t)b * NPT * CIN;

    #pragma unroll
    for (int e = 0; e < 8; ++e)
        sqm[e * 256 + t] = sqh[b * NPT + e * 256 + t] + DBIAS;

    stage_pts(xhb, bufA, q0, t);
    __syncthreads();

    f16x8 af[4][4];
    #pragma unroll
    for (int qh = 0; qh < 4; ++qh)
        #pragma unroll
        for (int ks = 0; ks < 4; ++ks)
            af[qh][ks] = *(const f16x8*)(bufA + (size_t)((qh * 4 + ks) * 64 + lane) * 8);
    __syncthreads();

    _Float16* wbuf = (_Float16*)(smraw + 26624 + wv * 8192);
    float*    DtW  = (float*)(smraw + wv * 4608);
    const _Float16* srcl = xhb + (size_t)(wv * 16 + l15) * CIN + quad * 8;
    stage_tile16(srcl, wbuf);

    float bd[KEEP];
    #pragma unroll
    for (int i = 0; i < KEEP; ++i) bd[i] = 3.0e38f;

    #pragma unroll 1
    for (int ss = 0; ss < 32; ++ss) {
        const int mb = ss * 64 + wv * 16;
        asm volatile("s_waitcnt vmcnt(0)" ::: "memory");
        __builtin_amdgcn_sched_barrier(0);
        const _Float16* cur = wbuf + (ss & 1) * 2048;
        f16x8 bf[4];
        #pragma unroll
        for (int ks = 0; ks < 4; ++ks)
            bf[ks] = *(const f16x8*)(cur + ks * 512 + lane * 8);
        float sm_ = sqm[mb + l15];
        asm volatile("s_waitcnt lgkmcnt(0)" ::: "memory");
        __builtin_amdgcn_sched_barrier(0);
        if (ss < 31)
            stage_tile16(srcl + (size_t)(ss + 1) * 64 * CIN,
                         wbuf + ((ss + 1) & 1) * 2048);
        __builtin_amdgcn_sched_barrier(0);
        f32x4 acc[4];
        #pragma unroll
        for (int qh = 0; qh < 4; ++qh) acc[qh] = (f32x4){0.f, 0.f, 0.f, 0.f};
        #pragma unroll
        for (int ks = 0; ks < 4; ++ks)
            #pragma unroll
            for (int qh = 0; qh < 4; ++qh)
                acc[qh] = __builtin_amdgcn_mfma_f32_16x16x32_f16(af[qh][ks], bf[ks], acc[qh], 0, 0, 0);
        const unsigned om = (unsigned)(mb + l15);
        #pragma unroll
        for (int qh = 0; qh < 4; ++qh) {
            #pragma unroll
            for (int rg = 0; rg < 4; ++rg) {
                int q = qh * 16 + quad * 4 + rg;
                float d = sm_ - 2.f * acc[qh][rg];
                DtW[q * 18 + l15] = __uint_as_float((__float_as_uint(d) & 0xFFFFF800u) | om);
            }
        }
        float nk[16];
        {
            const float* myrow = DtW + lane * 18;
            #pragma unroll
            for (int p = 0; p < 8; ++p) {
                f32x2 v = *(const f32x2*)(myrow + 2 * p);
                nk[2 * p] = v[0]; nk[2 * p + 1] = v[1];
            }
        }
        #pragma unroll
        for (int kk = 2; kk <= 16; kk <<= 1) {
            #pragma unroll
            for (int j = kk >> 1; j > 0; j >>= 1) {
                #pragma unroll
                for (int i = 0; i < 16; ++i) {
                    int p = i ^ j;
                    if (p > i) {
                        float a = nk[i], c = nk[p];
                        float lo = fminf(a, c), hi = fmaxf(a, c);
                        if ((i & kk) == 0) { nk[i] = lo; nk[p] = hi; }
                        else               { nk[i] = hi; nk[p] = lo; }
                    }
                }
            }
        }
        #pragma unroll
        for (int i = 0; i < 16; ++i) bd[i] = fminf(bd[i], nk[15 - i]);
        #pragma unroll
        for (int j = 8; j > 0; j >>= 1) {
            #pragma unroll
            for (int i = 0; i < 16; ++i) {
                int p = i ^ j;
                if (p > i) {
                    float a = bd[i], c = bd[p];
                    bd[i] = fminf(a, c);
                    bd[p] = fmaxf(a, c);
                }
            }
        }
    }

    __syncthreads();

    float*  Keys = (float*)smraw;
    int*    Surv = (int*)(smraw + 16640);
    double* ddL  = (double*)(smraw + 25088);
    #pragma unroll
    for (int i = 0; i < KEEP; ++i)
        Keys[lane * 65 + wv * KEEP + i] = bd[i];
    __syncthreads();
    {
        int cnt[KEEP];
        #pragma unroll
        for (int i = 0; i < KEEP; ++i) cnt[i] = 0;
        #pragma unroll 4
        for (int j = 0; j < 64; ++j) {
            float kj = Keys[lane * 65 + j];
            #pragma unroll
            for (int i = 0; i < KEEP; ++i)
                cnt[i] += (kj < bd[i]) ? 1 : 0;
        }
        __syncthreads();
        #pragma unroll
        for (int i = 0; i < KEEP; ++i)
            if (cnt[i] < SIFT)
                Surv[lane * 33 + cnt[i]] = (int)(__float_as_uint(bd[i]) & 0x7FFu);
    }
    __syncthreads();

    int ms[8];
    #pragma unroll
    for (int k = 0; k < 8; ++k) ms[k] = Surv[lane * 33 + wv * 8 + k] & 2047;
    double dd8[8];
    #pragma unroll
    for (int k = 0; k < 8; ++k) dd8[k] = 0.0;
    const float* xTb = xT + (size_t)b * NPT * CIN;
    const float* qrow = xTb + (size_t)(q0 + lane) * CIN;
    #pragma unroll 1
    for (int ch = 0; ch < 8; ++ch) {
        double qd[16];
        #pragma unroll
        for (int j = 0; j < 4; ++j) {
            float4 qv = *(const float4*)&qrow[ch * 16 + 4 * j];
            qd[4 * j] = (double)qv.x; qd[4 * j + 1] = (double)qv.y;
            qd[4 * j + 2] = (double)qv.z; qd[4 * j + 3] = (double)qv.w;
        }
        #pragma unroll
        for (int k = 0; k < 8; ++k) {
            const float* mrow = xTb + (size_t)ms[k] * CIN + ch * 16;
            float4 ma = *(const float4*)&mrow[0];
            float4 mb2 = *(const float4*)&mrow[4];
            float4 mc = *(const float4*)&mrow[8];
            float4 md = *(const float4*)&mrow[12];
            double ss = dd8[k], d0;
            d0 = qd[0]  - (double)ma.x;  ss = fma(d0, d0, ss);
            d0 = qd[1]  - (double)ma.y;  ss = fma(d0, d0, ss);
            d0 = qd[2]  - (double)ma.z;  ss = fma(d0, d0, ss);
            d0 = qd[3]  - (double)ma.w;  ss = fma(d0, d0, ss);
            d0 = qd[4]  - (double)mb2.x; ss = fma(d0, d0, ss);
            d0 = qd[5]  - (double)mb2.y; ss = fma(d0, d0, ss);
            d0 = qd[6]  - (double)mb2.z; ss = fma(d0, d0, ss);
            d0 = qd[7]  - (double)mb2.w; ss = fma(d0, d0, ss);
            d0 = qd[8]  - (double)mc.x;  ss = fma(d0, d0, ss);
            d0 = qd[9]  - (double)mc.y;  ss = fma(d0, d0, ss);
            d0 = qd[10] - (double)mc.z;  ss = fma(d0, d0, ss);
            d0 = qd[11] - (double)mc.w;  ss = fma(d0, d0, ss);
            d0 = qd[12] - (double)md.x;  ss = fma(d0, d0, ss);
            d0 = qd[13] - (double)md.y;  ss = fma(d0, d0, ss);
            d0 = qd[14] - (double)md.z;  ss = fma(d0, d0, ss);
            d0 = qd[15] - (double)md.w;  ss = fma(d0, d0, ss);
            dd8[k] = ss;
        }
    }
    #pragma unroll
    for (int k = 0; k < 8; ++k) ddL[lane * 33 + wv * 8 + k] = dd8[k];
    __syncthreads();
    int* dst = knn_out + ((size_t)b * NPT + q0 + lane) * KNN;
    #pragma unroll
    for (int k = 0; k < 8; ++k) {
        int c = 0;
        #pragma unroll 4
        for (int j = 0; j < SIFT; ++j)
            c += (ddL[lane * 33 + j] < dd8[k]) ? 1 : 0;
        if (c < KNN) dst[c] = ms[k];
    }
}

// ------------------------------------------------- u/v GEMM via fp16 MFMA
// 1D 512-block grid, XCD-pinned. Outputs stored as fp16 (u,v already carry
// fp16-GEMM error; storage rounding adds ~2^-11 relative -- smooth, no rank
// decisions downstream except vmax/vmin which remain monotone).
__global__ __launch_bounds__(256) void uv_gemm_h(const _Float16* __restrict__ xhT,
                                                 const _Float16* __restrict__ Wu,
                                                 const _Float16* __restrict__ Wv,
                                                 _Float16* __restrict__ uT,
                                                 _Float16* __restrict__ vT) {
    __shared__ _Float16 Bx[8192];                  // 64 n x 128 c, fragment order
    const int id  = blockIdx.x;                    // 512, XCD-pinned
    const int xcd = id & 7, qq = id >> 3;          // qq 0..63
    const int b   = xcd + ((qq >> 5) << 3);
    const int n0  = (qq & 31) * 64;
    const int t = threadIdx.x;
    const int lane = t & 63, w = t >> 6, l15 = lane & 15, quad = lane >> 4;
    stage_pts(xhT + (size_t)b * NPT * CIN, Bx, n0, t);
    __syncthreads();
    f16x8 bf[4];
    #pragma unroll
    for (int ks = 0; ks < 4; ++ks)
        bf[ks] = *(const f16x8*)(Bx + (size_t)((w * 4 + ks) * 64 + lane) * 8);
    const int n = n0 + w * 16 + l15;
    #pragma unroll 1
    for (int ot = 0; ot < 16; ++ot) {
        const _Float16* wu = Wu + (size_t)(ot * 16 + l15) * 128 + quad * 8;
        const _Float16* wv2 = Wv + (size_t)(ot * 16 + l15) * 128 + quad * 8;
        f32x4 au = (f32x4){0.f, 0.f, 0.f, 0.f};
        f32x4 av = (f32x4){0.f, 0.f, 0.f, 0.f};
        #pragma unroll
        for (int ks = 0; ks < 4; ++ks) {
            f16x8 a_u = *(const f16x8*)(wu + ks * 32);
            f16x8 a_v = *(const f16x8*)(wv2 + ks * 32);
            au = __builtin_amdgcn_mfma_f32_16x16x32_f16(a_u, bf[ks], au, 0, 0, 0);
            av = __builtin_amdgcn_mfma_f32_16x16x32_f16(a_v, bf[ks], av, 0, 0, 0);
        }
        size_t base = ((size_t)b * NPT + n) * COUT + ot * 16 + quad * 4;
        f16x4 auh = {(_Float16)au[0], (_Float16)au[1], (_Float16)au[2], (_Float16)au[3]};
        f16x4 avh = {(_Float16)av[0], (_Float16)av[1], (_Float16)av[2], (_Float16)av[3]};
        *(f16x4*)&uT[base] = auh;
        *(f16x4*)&vT[base] = avh;
    }
}

// ------------------------------------------------- legacy fp32 u/v GEMM (fallback)
__global__ __launch_bounds__(256) void uv_gemm(const float* __restrict__ x,
                                               const float* __restrict__ W,
                                               float* __restrict__ uT,
                                               float* __restrict__ vT) {
    __shared__ float Ax[32 * 64];
    __shared__ float Bu[32 * 68];
    __shared__ float Bv[32 * 68];
    const int b  = blockIdx.z;
    const int n0 = blockIdx.x * 64;
    const int o0 = blockIdx.y * 64;
    const int t  = threadIdx.x;
    const int tx = t & 15, ty = t >> 4;
    const float* xb = x + (size_t)b * CIN * NPT;
    float au[4][4], av_[4][4];
    #pragma unroll
    for (int i = 0; i < 4; ++i)
        #pragma unroll
        for (int j = 0; j < 4; ++j) { au[i][j] = 0.f; av_[i][j] = 0.f; }
    #pragma unroll 1
    for (int kc = 0; kc < 4; ++kc) {
        const int c0 = kc * 32;
        __syncthreads();
        #pragma unroll
        for (int e = 0; e < 2; ++e) {
            int f = e * 256 + t;
            int cz = f >> 4, ni = (f & 15) << 2;
            *(float4*)&Ax[(cz << 6) + ni] = *(const float4*)&xb[(size_t)(c0 + cz) * NPT + n0 + ni];
        }
        #pragma unroll
        for (int e = 0; e < 8; ++e) {
            int ii = e * 256 + t;
            int cz = ii & 31, oj = ii >> 5;
            float w1 = W[(size_t)(o0 + oj) * 256 + c0 + cz];
            float w2 = W[(size_t)(o0 + oj) * 256 + 128 + c0 + cz];
            Bu[cz * 68 + oj] = w1 - w2;
            Bv[cz * 68 + oj] = w2;
        }
        __syncthreads();
        #pragma unroll 8
        for (int cz = 0; cz < 32; ++cz) {
            const float4 a4 = *(const float4*)&Ax[(cz << 6) + (tx << 2)];
            float bu0 = Bu[cz * 68 + (ty << 2) + 0], bv0 = Bv[cz * 68 + (ty << 2) + 0];
            float bu1 = Bu[cz * 68 + (ty << 2) + 1], bv1 = Bv[cz * 68 + (ty << 2) + 1];
            float bu2 = Bu[cz * 68 + (ty << 2) + 2], bv2 = Bv[cz * 68 + (ty << 2) + 2];
            float bu3 = Bu[cz * 68 + (ty << 2) + 3], bv3 = Bv[cz * 68 + (ty << 2) + 3];
            au[0][0] += a4.x * bu0; au[0][1] += a4.x * bu1; au[0][2] += a4.x * bu2; au[0][3] += a4.x * bu3;
            au[1][0] += a4.y * bu0; au[1][1] += a4.y * bu1; au[1][2] += a4.y * bu2; au[1][3] += a4.y * bu3;
            au[2][0] += a4.z * bu0; au[2][1] += a4.z * bu1; au[2][2] += a4.z * bu2; au[2][3] += a4.z * bu3;
            au[3][0] += a4.w * bu0; au[3][1] += a4.w * bu1; au[3][2] += a4.w * bu2; au[3][3] += a4.w * bu3;
            av_[0][0] += a4.x * bv0; av_[0][1] += a4.x * bv1; av_[0][2] += a4.x * bv2; av_[0][3] += a4.x * bv3;
            av_[1][0] += a4.y * bv0; av_[1][1] += a4.y * bv1; av_[1][2] += a4.y * bv2; av_[1][3] += a4.y * bv3;
            av_[2][0] += a4.z * bv0; av_[2][1] += a4.z * bv1; av_[2][2] += a4.z * bv2; av_[2][3] += a4.z * bv3;
            av_[3][0] += a4.w * bv0; av_[3][1] += a4.w * bv1; av_[3][2] += a4.w * bv2; av_[3][3] += a4.w * bv3;
        }
    }
    #pragma unroll
    for (int i = 0; i < 4; ++i) {
        int n = n0 + (tx << 2) + i;
        size_t base = ((size_t)b * NPT + n) * COUT + o0 + (ty << 2);
        float4 u4 = {au[i][0], au[i][1], au[i][2], au[i][3]};
        float4 v4 = {av_[i][0], av_[i][1], av_[i][2], av_[i][3]};
        *(float4*)&uT[base] = u4;
        *(float4*)&vT[base] = v4;
    }
}

// ------------------------------------------------- fused gather+stats (pass A)
// 2048 blocks XCD-pinned (fp16 vT slice = 1 MB/batch, 2 MB/XCD in L2).
// fp16 u/v in, fp32 compute, fp16 y1/y2 out (nontemporal). BN sums in double.
__global__ __launch_bounds__(256) void gather_stats(const _Float16* __restrict__ uT,
                                                    const _Float16* __restrict__ vT,
                                                    const int* __restrict__ knn_in,
                                                    double* __restrict__ gsum,
                                                    _Float16* __restrict__ aMax,
                                                    _Float16* __restrict__ aMin) {
    __shared__ int sidx[16 * KNN];
    const int id  = blockIdx.x;                    // 2048, XCD-pinned
    const int xcd = id & 7, qq = id >> 3;          // qq 0..255
    const int b   = xcd + ((qq >> 7) << 3);
    const int inner = qq & 127;
    const int n0  = (inner >> 2) * 64 + (inner & 3) * 16;
    const int o   = threadIdx.x;
    for (int e = o; e < 16 * KNN; e += 256)
        sidx[e] = knn_in[((size_t)b * NPT + n0) * KNN + e];
    __syncthreads();
    const _Float16* ub = uT + ((size_t)b * NPT + n0) * COUT + o;
    const _Float16* vb = vT + (size_t)b * NPT * COUT + o;
    _Float16* amx = aMax + ((size_t)b * NPT + n0) * COUT + o;
    _Float16* amn = aMin + ((size_t)b * NPT + n0) * COUT + o;
    double s1 = 0.0, s2 = 0.0;
    #pragma unroll 1
    for (int s = 0; s < 16; ++s) {
        float u = (float)ub[(size_t)s * COUT];
        float vmax = -3e38f, vmin = 3e38f, vsum = 0.f, vsq = 0.f;
        #pragma unroll
        for (int j = 0; j < KNN; ++j) {
            float v = (float)vb[(size_t)sidx[s * KNN + j] * COUT];
            vmax = fmaxf(vmax, v);
            vmin = fminf(vmin, v);
            vsum += v;
            vsq = fmaf(v, v, vsq);
        }
        s1 += 20.0 * (double)u + (double)vsum;
        s2 += 20.0 * (double)u * (double)u + 2.0 * (double)u * (double)vsum + (double)vsq;
        _Float16 y1 = (_Float16)(u + vmax);        // == max_j (u+v_j), RN monotone
        _Float16 y2 = (_Float16)(u + vmin);
        __builtin_nontemporal_store(y1, &amx[(size_t)s * COUT]);
        __builtin_nontemporal_store(y2, &amn[(size_t)s * COUT]);
    }
    atomicAdd(&gsum[o], s1);
    atomicAdd(&gsum[COUT + o], s2);
}

// ------------------------------------------------- BN statistics (legacy pass A)
__global__ __launch_bounds__(256) void stats_kernel(const float* __restrict__ uT,
                                                    const float* __restrict__ vT,
                                                    const int* __restrict__ knn_in,
                                                    double* __restrict__ gsum) {
    __shared__ int sidx[64 * KNN];
    const int b  = blockIdx.y;
    const int n0 = blockIdx.x * 64;
    const int o  = threadIdx.x;
    for (int e = o; e < 64 * KNN; e += 256)
        sidx[e] = knn_in[((size_t)b * NPT + n0) * KNN + e];
    __syncthreads();
    const float* ub = uT + ((size_t)b * NPT + n0) * COUT + o;
    const float* vb = vT + (size_t)b * NPT * COUT + o;
    double s1 = 0.0, s2 = 0.0;
    #pragma unroll 1
    for (int s = 0; s < 64; ++s) {
        float u = ub[(size_t)s * COUT];
        #pragma unroll
        for (int j = 0; j < KNN; ++j) {
            float y = u + vb[(size_t)sidx[s * KNN + j] * COUT];
            s1 += (double)y;
            s2 = fma((double)y, (double)y, s2);
        }
    }
    atomicAdd(&gsum[o], s1);
    atomicAdd(&gsum[COUT + o], s2);
}

// ------------------------------------------------- fold stats -> scale/shift
__global__ void finalize_kernel(const double* __restrict__ gsum,
                                const float* __restrict__ gamma,
                                const float* __restrict__ beta,
                                float* __restrict__ st) {
    const int o = threadIdx.x;
    const double M = (double)B_ * NPT * KNN;
    double mean = gsum[o] / M;
    double var  = gsum[COUT + o] / M - mean * mean;
    float inv = 1.0f / sqrtf((float)var + EPS);
    float s = gamma[o] * inv;
    st[o] = s;
    st[COUT + o] = beta[o] - (float)mean * s;
}

// ------------------------------------------------- out from fp16 y1/y2 (fused)
// 1D 512-block grid, XCD-pinned; folds finalize in (each thread derives
// s/tt from gsum directly -- stream order guarantees atomics complete).
__global__ __launch_bounds__(256, 2) void out2_kernel(const _Float16* __restrict__ aMax,
                                                      const _Float16* __restrict__ aMin,
                                                      const double* __restrict__ gsum,
                                                      const float* __restrict__ gamma,
                                                      const float* __restrict__ beta,
                                                      float* __restrict__ out) {
    __shared__ float zt[256 * 68];
    const int id  = blockIdx.x;                    // 512, XCD-pinned
    const int xcd = id & 7, qq = id >> 3;          // qq 0..63
    const int b   = xcd + ((qq >> 5) << 3);
    const int n0  = (qq & 31) * 64;
    const int o = threadIdx.x;
    const double M = (double)B_ * NPT * KNN;
    double mean = gsum[o] / M;
    double var  = gsum[COUT + o] / M - mean * mean;
    float inv = 1.0f / sqrtf((float)var + EPS);
    const float s  = gamma[o] * inv;
    const float tt = beta[o] - (float)mean * s;
    const _Float16* amx = aMax + ((size_t)b * NPT + n0) * COUT + o;
    const _Float16* amn = aMin + ((size_t)b * NPT + n0) * COUT + o;
    #pragma unroll 2
    for (int si = 0; si < 64; ++si) {
        float y1 = (float)amx[(size_t)si * COUT];
        float y2 = (float)amn[(size_t)si * COUT];
        float z1 = fmaxf(s * y1 + tt, 0.f);
        float z2 = fmaxf(s * y2 + tt, 0.f);
        zt[o * 68 + si] = fmaxf(z1, z2);
    }
    __syncthreads();
    float* dst = out + ((size_t)b * COUT + o) * NPT + n0;
    #pragma unroll
    for (int i = 0; i < 16; ++i)
        *(float4*)&dst[i * 4] = *(const float4*)&zt[o * 68 + i * 4];
}

// ------------------------------------------------- legacy gather+affine+relu+max
__global__ __launch_bounds__(256, 2) void out_kernel(const float* __restrict__ uT,
                                                     const float* __restrict__ vT,
                                                     const int* __restrict__ knn_in,
                                                     const float* __restrict__ st,
                                                     float* __restrict__ out) {
    __shared__ int sidx[64 * KNN];
    __shared__ float zt[256 * 68];
    const int b  = blockIdx.y;
    const int n0 = blockIdx.x * 64;
    const int o  = threadIdx.x;
    for (int e = o; e < 64 * KNN; e += 256)
        sidx[e] = knn_in[((size_t)b * NPT + n0) * KNN + e];
    __syncthreads();
    const float s  = st[o];
    const float tt = st[COUT + o];
    const float* ub = uT + ((size_t)b * NPT + n0) * COUT + o;
    const float* vb = vT + (size_t)b * NPT * COUT + o;
    #pragma unroll 1
    for (int si = 0; si < 64; ++si) {
        float u = ub[(size_t)si * COUT];
        float ymax = -3e38f, ymin = 3e38f;
        #pragma unroll
        for (int j = 0; j < KNN; ++j) {
            float y = u + vb[(size_t)sidx[si * KNN + j] * COUT];
            ymax = fmaxf(ymax, y);
            ymin = fminf(ymin, y);
        }
        float z1 = fmaxf(s * ymax + tt, 0.f);
        float z2 = fmaxf(s * ymin + tt, 0.f);
        zt[o * 68 + si] = fmaxf(z1, z2);
    }
    __syncthreads();
    float* dst = out + ((size_t)b * COUT + o) * NPT + n0;
    #pragma unroll
    for (int i = 0; i < 16; ++i)
        *(float4*)&dst[i * 4] = *(const float4*)&zt[o * 68 + i * 4];
}

extern "C" void kernel_launch(void* const* d_in, const int* in_sizes, int n_in,
                              void* d_out, int out_size, void* d_ws, size_t ws_size,
                              hipStream_t stream) {
    const float* x     = (const float*)d_in[0];
    const float* W     = (const float*)d_in[1];
    const float* gamma = (const float*)d_in[2];
    const float* beta  = (const float*)d_in[3];
    float* out = (float*)d_out;
    char* ws = (char*)d_ws;
    float*     sqh  = (float*)(ws + SQ_OFF);
    int*       idx  = (int*)(ws + IDX_OFF);
    double*    gsum = (double*)(ws + GS_OFF);
    float*     st   = (float*)(ws + ST_OFF);
    const bool fused = (ws_size >= WS_NEED_FUSED);

    if (fused) {
        // xT/xhT/Wu/Wv in the AMAX region (xT dead after refine; fp16 aMax
        // overwrites the xT slot). Survivor ids in the uT region (dead
        // until uv_gemm_h). uT/vT/aMax/aMin all fp16.
        float*    xT   = (float*)(ws + AMAX_OFF);
        _Float16* xhT  = (_Float16*)(ws + AMAX_OFF + 16777216ull);
        _Float16* Wu   = (_Float16*)(ws + AMAX_OFF + 25165824ull);
        _Float16* Wv   = (_Float16*)(ws + AMAX_OFF + 25231360ull);
        int*      svG  = (int*)(ws + UT_OFF);
        _Float16* uTh  = (_Float16*)(ws + UT_OFF);
        _Float16* vTh  = (_Float16*)(ws + VT_OFF);
        _Float16* aMxh = (_Float16*)(ws + AMAX_OFF);
        _Float16* aMnh = (_Float16*)(ws + AMIN_OFF);
        prep_kernel<<<512, 256, 0, stream>>>(x, W, xT, xhT, Wu, Wv, sqh, gsum);
        knn_kernel<<<512, 256, 0, stream>>>(xhT, sqh, svG);
        refine_kernel<<<2048, 256, 0, stream>>>(xT, svG, idx);
        uv_gemm_h<<<512, 256, 0, stream>>>(xhT, Wu, Wv, uTh, vTh);
        gather_stats<<<2048, 256, 0, stream>>>(uTh, vTh, idx, gsum, aMxh, aMnh);
        out2_kernel<<<512, 256, 0, stream>>>(aMxh, aMnh, gsum, gamma, beta, out);
    } else {
        // fallback: fp32 path; xT aliases uT, xhT aliases vT; fp32 uv after knn
        float*    xT  = (float*)(ws + XT_OFF);
        _Float16* xhT = (_Float16*)(ws + XHT_OFF);
        float*    uT  = (float*)(ws + UT_OFF);
        float*    vT  = (float*)(ws + VT_OFF);
        prep_kernel<<<512, 256, 0, stream>>>(x, W, xT, xhT, nullptr, nullptr, sqh, gsum);
        knn_kernel_fb<<<dim3(32, 16), 256, 0, stream>>>(xhT, xT, sqh, idx);
        uv_gemm<<<dim3(32, 4, 16), 256, 0, stream>>>(x, W, uT, vT);
        stats_kernel<<<dim3(32, 16), 256, 0, stream>>>(uT, vT, idx, gsum);
        finalize_kernel<<<1, 256, 0, stream>>>(gsum, gamma, beta, st);
        out_kernel<<<dim3(32, 16), 256, 0, stream>>>(uT, vT, idx, st, out);
    }
}